// Round 1
// baseline (2198.466 us; speedup 1.0000x reference)
//
#include <hip/hip_runtime.h>
#include <hip/hip_bf16.h>
#include <stdint.h>

typedef unsigned short u16;
typedef short bf16x8 __attribute__((ext_vector_type(8)));
typedef float f32x4 __attribute__((ext_vector_type(4)));

#define N_CLS  512
#define N_CTXT 16
#define DIM    768
#define VOCAB  49408
#define NROWS  (N_CLS*N_CTXT)   /* 8192 */
#define SUFL   60
#define SEQ    77
#define VTILES (VOCAB/128)      /* 386 */
#define VSPLIT 8
#define KSTEPS (DIM/32)         /* 24 */

// ---------------- async global->LDS (16B/lane) ----------------
__device__ __forceinline__ void gl2lds16(const void* g, void* l) {
  __builtin_amdgcn_global_load_lds(
      (const __attribute__((address_space(1))) unsigned int*)g,
      (__attribute__((address_space(3))) unsigned int*)l, 16, 0, 0);
}

// ---------------- row sum-of-squares (x2 / e2) ----------------
__global__ __launch_bounds__(256) void rowsq_kernel(const float* __restrict__ src,
                                                    float* __restrict__ dst) {
  const size_t row = blockIdx.x;
  const float* p = src + row * DIM;
  const int t = threadIdx.x;
  float ss = 0.f;
#pragma unroll
  for (int j = 0; j < 3; ++j) { float f = p[t + j * 256]; ss += f * f; }
#pragma unroll
  for (int m = 1; m < 64; m <<= 1) ss += __shfl_xor(ss, m, 64);
  __shared__ float sred[4];
  if ((t & 63) == 0) sred[t >> 6] = ss;
  __syncthreads();
  if (t == 0) dst[row] = (sred[0] + sred[1]) + (sred[2] + sred[3]);
}

// ---------------- exact truncation split: f32 -> bf16 hi + bf16 lo ----------------
// hi = top 16 bits of f (truncate); lo = f - hi (exactly representable in bf16).
__device__ __forceinline__ void split1(float f, u16& h, u16& l) {
  unsigned int b = __float_as_uint(f);
  h = (u16)(b >> 16);
  float r = f - __uint_as_float(b & 0xffff0000u);
  l = (u16)(__float_as_uint(r) >> 16);
}

__global__ __launch_bounds__(256) void split_x_kernel(const float* __restrict__ X,
                                                      u16* __restrict__ hi,
                                                      u16* __restrict__ lo) {
  int i = blockIdx.x * 256 + threadIdx.x;      // over float4, total 1,572,864
  if (i >= (NROWS * DIM) / 4) return;
  float4 v = ((const float4*)X)[i];
  u16 h0, h1, h2, h3, l0, l1, l2, l3;
  split1(v.x, h0, l0); split1(v.y, h1, l1); split1(v.z, h2, l2); split1(v.w, h3, l3);
  ((ushort4*)hi)[i] = make_ushort4(h0, h1, h2, h3);
  ((ushort4*)lo)[i] = make_ushort4(l0, l1, l2, l3);
}

__global__ __launch_bounds__(256) void split_e_kernel(const float* __restrict__ E,
                                                      u16* __restrict__ hi,
                                                      u16* __restrict__ lo,
                                                      float* __restrict__ e2) {
  const size_t row = blockIdx.x;
  const int t = threadIdx.x;
  const float* src = E + row * DIM;
  float ss = 0.f;
#pragma unroll
  for (int j = 0; j < 3; ++j) {
    int k = t + j * 256;
    float f = src[k];
    u16 h, l;
    split1(f, h, l);
    hi[row * DIM + k] = h;
    lo[row * DIM + k] = l;
    ss += f * f;
  }
#pragma unroll
  for (int m = 1; m < 64; m <<= 1) ss += __shfl_xor(ss, m, 64);
  __shared__ float sred[4];
  if ((t & 63) == 0) sred[t >> 6] = ss;
  __syncthreads();
  if (t == 0) e2[row] = (sred[0] + sred[1]) + (sred[2] + sred[3]);
}

// ---------------- fused split-bf16 GEMM + running argmin ----------------
// block tile 128 rows x 128 vocab, BK=32, 4 waves in 2x2 quadrants (64x64 each).
// dot accumulated as 4 bf16 MFMAs (hh+hl+lh+ll) into one fp32 acc -> fp32-exact product sum.
__global__ __launch_bounds__(256, 2)
void gemm_argmin(const u16* __restrict__ Xhi, const u16* __restrict__ Xlo,
                 const u16* __restrict__ Ehi, const u16* __restrict__ Elo,
                 const float* __restrict__ e2, const float* __restrict__ x2,
                 float* __restrict__ pval, int* __restrict__ pidx) {
  __shared__ u16 sm[16384];          // 32KB: Ahi|Alo|Bhi|Blo, each 128x32 bf16 (8KB)
  __shared__ float bestv_s[2][128];
  __shared__ int   besti_s[2][128];

  const int tid = threadIdx.x;
  const int w = tid >> 6, l = tid & 63;
  const int qr = w >> 1, qc = w & 1;   // wave quadrant: row half / col half
  const int lr = l & 15, lk = l >> 4;  // frag row, frag k-group
  const int mbase = blockIdx.x * 128;

  // staging map: per region (8KB = 128 rows x 64B), wave w covers [w*2048, w*2048+2048)
  // as two 1KB chunks; lane lands at base + l*16 (matches global_load_lds semantics).
  const int o1 = w * 2048 + l * 16;
  const int o2 = o1 + 1024;
  const int row1 = o1 >> 6, kb1 = o1 & 63;
  const int row2 = o2 >> 6, kb2 = o2 & 63;

  const char* aHi1 = (const char*)Xhi + (size_t)(mbase + row1) * (DIM * 2) + kb1;
  const char* aHi2 = (const char*)Xhi + (size_t)(mbase + row2) * (DIM * 2) + kb2;
  const char* aLo1 = (const char*)Xlo + (size_t)(mbase + row1) * (DIM * 2) + kb1;
  const char* aLo2 = (const char*)Xlo + (size_t)(mbase + row2) * (DIM * 2) + kb2;

  char* smc = (char*)sm;
  char* dAh1 = smc + o1;          char* dAh2 = smc + o2;
  char* dAl1 = smc + 8192 + o1;   char* dAl2 = smc + 8192 + o2;
  char* dBh1 = smc + 16384 + o1;  char* dBh2 = smc + 16384 + o2;
  char* dBl1 = smc + 24576 + o1;  char* dBl2 = smc + 24576 + o2;

  float bv[16];
  int bi[16];
#pragma unroll
  for (int s = 0; s < 16; ++s) { bv[s] = INFINITY; bi[s] = 0x7fffffff; }

  for (int vt = blockIdx.y; vt < VTILES; vt += VSPLIT) {
    const char* bHi1 = (const char*)Ehi + (size_t)(vt * 128 + row1) * (DIM * 2) + kb1;
    const char* bHi2 = (const char*)Ehi + (size_t)(vt * 128 + row2) * (DIM * 2) + kb2;
    const char* bLo1 = (const char*)Elo + (size_t)(vt * 128 + row1) * (DIM * 2) + kb1;
    const char* bLo2 = (const char*)Elo + (size_t)(vt * 128 + row2) * (DIM * 2) + kb2;

    f32x4 acc[4][4];
#pragma unroll
    for (int a = 0; a < 4; ++a)
#pragma unroll
      for (int b = 0; b < 4; ++b) { f32x4 z = {0.f, 0.f, 0.f, 0.f}; acc[a][b] = z; }

    for (int ks = 0; ks < KSTEPS; ++ks) {
      const int kb = ks * 64;  // BK=32 bf16 = 64 bytes along K
      __syncthreads();         // previous compute done before LDS overwrite
      gl2lds16(aHi1 + kb, dAh1); gl2lds16(aHi2 + kb, dAh2);
      gl2lds16(aLo1 + kb, dAl1); gl2lds16(aLo2 + kb, dAl2);
      gl2lds16(bHi1 + kb, dBh1); gl2lds16(bHi2 + kb, dBh2);
      gl2lds16(bLo1 + kb, dBl1); gl2lds16(bLo2 + kb, dBl2);
      __syncthreads();         // compiler drains vmcnt(0) before barrier

      bf16x8 ah[4], al_[4];
#pragma unroll
      for (int f = 0; f < 4; ++f) {
        int ra = (qr * 64 + f * 16 + lr) * 32 + lk * 8;
        ah[f]  = *(const bf16x8*)(sm + ra);
        al_[f] = *(const bf16x8*)(sm + 4096 + ra);
      }
#pragma unroll
      for (int fn = 0; fn < 4; ++fn) {
        int rb = (qc * 64 + fn * 16 + lr) * 32 + lk * 8;
        bf16x8 bh  = *(const bf16x8*)(sm + 8192 + rb);
        bf16x8 bl_ = *(const bf16x8*)(sm + 12288 + rb);
#pragma unroll
        for (int fm = 0; fm < 4; ++fm) {
          f32x4 c = acc[fm][fn];
          c = __builtin_amdgcn_mfma_f32_16x16x32_bf16(ah[fm], bh, c, 0, 0, 0);
          c = __builtin_amdgcn_mfma_f32_16x16x32_bf16(ah[fm], bl_, c, 0, 0, 0);
          c = __builtin_amdgcn_mfma_f32_16x16x32_bf16(al_[fm], bh, c, 0, 0, 0);
          c = __builtin_amdgcn_mfma_f32_16x16x32_bf16(al_[fm], bl_, c, 0, 0, 0);
          acc[fm][fn] = c;
        }
      }
    }

    // epilogue: score = (x2 - 2*dot) + e2  (reference rounding order), running argmin
#pragma unroll
    for (int fn = 0; fn < 4; ++fn) {
      const int vv = vt * 128 + qc * 64 + fn * 16 + lr;
      const float ev = e2[vv];
#pragma unroll
      for (int fm = 0; fm < 4; ++fm) {
#pragma unroll
        for (int r = 0; r < 4; ++r) {
          const int slot = fm * 4 + r;
          const float xx = x2[mbase + qr * 64 + fm * 16 + lk * 4 + r];
          float s = (xx - 2.0f * acc[fm][fn][r]) + ev;
          if (s < bv[slot]) { bv[slot] = s; bi[slot] = vv; }  // ascending v => first-min kept
        }
      }
    }
  }

  // reduce across the 16 lanes (lr) sharing each row
#pragma unroll
  for (int s = 0; s < 16; ++s) {
    float v_ = bv[s]; int i_ = bi[s];
#pragma unroll
    for (int m = 1; m < 16; m <<= 1) {
      float ov = __shfl_xor(v_, m, 64);
      int oi = __shfl_xor(i_, m, 64);
      if (ov < v_ || (ov == v_ && oi < i_)) { v_ = ov; i_ = oi; }
    }
    bv[s] = v_; bi[s] = i_;
  }
  if (lr == 0) {
#pragma unroll
    for (int s = 0; s < 16; ++s) {
      int row_local = qr * 64 + (s >> 2) * 16 + lk * 4 + (s & 3);
      bestv_s[qc][row_local] = bv[s];
      besti_s[qc][row_local] = bi[s];
    }
  }
  __syncthreads();
  if (tid < 128) {
    float v0 = bestv_s[0][tid]; int i0 = besti_s[0][tid];
    float v1 = bestv_s[1][tid]; int i1 = besti_s[1][tid];
    if (v1 < v0 || (v1 == v0 && i1 < i0)) { v0 = v1; i0 = i1; }
    pval[blockIdx.y * NROWS + mbase + tid] = v0;
    pidx[blockIdx.y * NROWS + mbase + tid] = i0;
  }
}

// ---------------- fp32 fallback (only if ws too small for split planes) ----------------
__global__ __launch_bounds__(256)
void gemm_argmin_f32(const float* __restrict__ X, const float* __restrict__ E,
                     const float* __restrict__ e2, const float* __restrict__ x2,
                     float* __restrict__ pval, int* __restrict__ pidx) {
  __shared__ float xs[16 * DIM];
  __shared__ float bvs[4][16];
  __shared__ int bis[4][16];
  const int tid = threadIdx.x, w = tid >> 6, l = tid & 63;
  const int rbase = blockIdx.x * 16;
  for (int i = tid; i < 16 * DIM / 4; i += 256)
    ((float4*)xs)[i] = ((const float4*)(X + (size_t)rbase * DIM))[i];
  __syncthreads();
  float xx[16], bv[16];
  int bi[16];
#pragma unroll
  for (int r = 0; r < 16; ++r) { xx[r] = x2[rbase + r]; bv[r] = INFINITY; bi[r] = 0x7fffffff; }
  const int c0 = blockIdx.y * (VOCAB / 16);
  for (int v = c0 + w; v < c0 + VOCAB / 16; v += 4) {
    const float* evp = E + (size_t)v * DIM;
    float part[16];
#pragma unroll
    for (int r = 0; r < 16; ++r) part[r] = 0.f;
#pragma unroll
    for (int j = 0; j < 12; ++j) {
      float e = evp[l + 64 * j];
#pragma unroll
      for (int r = 0; r < 16; ++r) part[r] += e * xs[r * DIM + l + 64 * j];
    }
    float ee = e2[v];
#pragma unroll
    for (int r = 0; r < 16; ++r) {
      float d = part[r];
#pragma unroll
      for (int m = 1; m < 64; m <<= 1) d += __shfl_xor(d, m, 64);
      float s = (xx[r] - 2.0f * d) + ee;
      if (s < bv[r]) { bv[r] = s; bi[r] = v; }
    }
  }
  if (l == 0) {
#pragma unroll
    for (int r = 0; r < 16; ++r) { bvs[w][r] = bv[r]; bis[w][r] = bi[r]; }
  }
  __syncthreads();
  if (tid < 16) {
    float v0 = bvs[0][tid]; int i0 = bis[0][tid];
#pragma unroll
    for (int ww = 1; ww < 4; ++ww) {
      float v1 = bvs[ww][tid]; int i1 = bis[ww][tid];
      if (v1 < v0 || (v1 == v0 && i1 < i0)) { v0 = v1; i0 = i1; }
    }
    pval[blockIdx.y * NROWS + rbase + tid] = v0;
    pidx[blockIdx.y * NROWS + rbase + tid] = i0;
  }
}

// ---------------- partial argmin reduce ----------------
__global__ __launch_bounds__(256)
void reduce_partials(const float* __restrict__ pval, const int* __restrict__ pidx,
                     int* __restrict__ nearest, int nparts) {
  int r = blockIdx.x * 256 + threadIdx.x;
  if (r >= NROWS) return;
  float bv = pval[r];
  int bi = pidx[r];
  for (int s = 1; s < nparts; ++s) {
    float v = pval[(size_t)s * NROWS + r];
    int i = pidx[(size_t)s * NROWS + r];
    if (v < bv || (v == bv && i < bi)) { bv = v; bi = i; }
  }
  nearest[r] = bi;
}

// ---------------- output assembly: [prefix | E[nearest] | suffix] ----------------
__global__ __launch_bounds__(256)
void assemble(const float* __restrict__ pre, const float* __restrict__ suf,
              const float* __restrict__ E, const int* __restrict__ nearest,
              float* __restrict__ out) {
  const int cls = blockIdx.y;
  const int i4 = blockIdx.x * 256 + threadIdx.x;   // over float4 within one class row
  if (i4 >= SEQ * (DIM / 4)) return;
  const int p = i4 / (DIM / 4), d4 = i4 % (DIM / 4);
  const float4* src;
  if (p == 0)
    src = (const float4*)(pre + (size_t)cls * DIM) + d4;
  else if (p <= N_CTXT)
    src = (const float4*)(E + (size_t)nearest[cls * N_CTXT + (p - 1)] * DIM) + d4;
  else
    src = (const float4*)(suf + ((size_t)cls * SUFL + (p - 1 - N_CTXT)) * DIM) + d4;
  ((float4*)(out + ((size_t)cls * SEQ + p) * DIM))[d4] = *src;
}

// ---------------- launcher ----------------
extern "C" void kernel_launch(void* const* d_in, const int* in_sizes, int n_in,
                              void* d_out, int out_size, void* d_ws, size_t ws_size,
                              hipStream_t stream) {
  const float* ctx = (const float*)d_in[0];
  const float* emb = (const float*)d_in[1];
  const float* pre = (const float*)d_in[2];
  const float* suf = (const float*)d_in[3];
  float* out = (float*)d_out;
  char* ws = (char*)d_ws;

  size_t off = 0;
  auto take = [&](size_t n) { size_t o = off; off += (n + 255) & ~(size_t)255; return o; };
  const size_t o_e2 = take((size_t)VOCAB * 4);
  const size_t o_x2 = take((size_t)NROWS * 4);
  const size_t o_pv = take((size_t)16 * NROWS * 4);
  const size_t o_pi = take((size_t)16 * NROWS * 4);
  const size_t o_nr = take((size_t)NROWS * 4);
  const size_t o_xh = take((size_t)NROWS * DIM * 2);
  const size_t o_xl = take((size_t)NROWS * DIM * 2);
  const size_t o_eh = take((size_t)VOCAB * DIM * 2);
  const size_t o_el = take((size_t)VOCAB * DIM * 2);
  const size_t full_need = off;

  float* e2p = (float*)(ws + o_e2);
  float* x2p = (float*)(ws + o_x2);
  float* pv = (float*)(ws + o_pv);
  int* pi = (int*)(ws + o_pi);
  int* nr = (int*)(ws + o_nr);
  u16* xh = (u16*)(ws + o_xh);
  u16* xl = (u16*)(ws + o_xl);
  u16* eh = (u16*)(ws + o_eh);
  u16* el = (u16*)(ws + o_el);

  const bool full = ws_size >= full_need;

  rowsq_kernel<<<NROWS, 256, 0, stream>>>(ctx, x2p);
  if (full) {
    split_x_kernel<<<(NROWS * DIM / 4) / 256, 256, 0, stream>>>(ctx, xh, xl);
    split_e_kernel<<<VOCAB, 256, 0, stream>>>(emb, eh, el, e2p);
    gemm_argmin<<<dim3(NROWS / 128, VSPLIT), 256, 0, stream>>>(xh, xl, eh, el, e2p, x2p, pv, pi);
    reduce_partials<<<NROWS / 256, 256, 0, stream>>>(pv, pi, nr, VSPLIT);
  } else {
    rowsq_kernel<<<VOCAB, 256, 0, stream>>>(emb, e2p);
    gemm_argmin_f32<<<dim3(NROWS / 16, 16), 256, 0, stream>>>(ctx, emb, e2p, x2p, pv, pi);
    reduce_partials<<<NROWS / 256, 256, 0, stream>>>(pv, pi, nr, 16);
  }
  assemble<<<dim3((SEQ * (DIM / 4) + 255) / 256, N_CLS), 256, 0, stream>>>(pre, suf, emb, nr, out);
}